// Round 1
// baseline (124.952 us; speedup 1.0000x reference)
//
#include <hip/hip_runtime.h>

// B=8, H=W=256, single channel. Output: one fp32 scalar (composite loss).
#define HW_ELEMS 65536
#define BIGD 1e4f
#define EPSL 1e-8f

__device__ __forceinline__ float waveSum(float v) {
  #pragma unroll
  for (int off = 32; off > 0; off >>= 1) v += __shfl_down(v, off);
  return v;
}

// Per-batch sums: inter = sum p*t, sp = sum p, st = sum t; global attn SSE.
// acc layout (floats): [0..7]=inter, [8..15]=sum_p, [16..23]=sum_t, [24]=attn_sse, [25]=boundary_sum
__global__ __launch_bounds__(256) void reduce_kernel(
    const float* __restrict__ probs, const int* __restrict__ targets,
    const float* __restrict__ attn, float* __restrict__ acc) {
  const int b = blockIdx.y;
  const int base = b * HW_ELEMS + blockIdx.x * 2048 + threadIdx.x * 8;
  float inter = 0.f, sp = 0.f, st = 0.f, sse = 0.f;
  #pragma unroll
  for (int k = 0; k < 2; ++k) {
    const float4 p4 = *reinterpret_cast<const float4*>(probs + base + k * 4);
    const int4  t4 = *reinterpret_cast<const int4*>(targets + base + k * 4);
    const float4 a4 = *reinterpret_cast<const float4*>(attn + base + k * 4);
    const float pv[4] = {p4.x, p4.y, p4.z, p4.w};
    const float tv[4] = {(float)t4.x, (float)t4.y, (float)t4.z, (float)t4.w};
    const float av[4] = {a4.x, a4.y, a4.z, a4.w};
    #pragma unroll
    for (int j = 0; j < 4; ++j) {
      inter += pv[j] * tv[j];
      sp    += pv[j];
      st    += tv[j];
      const float d = av[j] - tv[j];
      sse += d * d;
    }
  }
  __shared__ float lds[4][4];
  const int wid = threadIdx.x >> 6, lane = threadIdx.x & 63;
  const float v0 = waveSum(inter), v1 = waveSum(sp), v2 = waveSum(st), v3 = waveSum(sse);
  if (lane == 0) { lds[wid][0] = v0; lds[wid][1] = v1; lds[wid][2] = v2; lds[wid][3] = v3; }
  __syncthreads();
  if (threadIdx.x == 0) {
    float s0 = 0.f, s1 = 0.f, s2 = 0.f, s3 = 0.f;
    #pragma unroll
    for (int w = 0; w < 4; ++w) { s0 += lds[w][0]; s1 += lds[w][1]; s2 += lds[w][2]; s3 += lds[w][3]; }
    atomicAdd(acc + b, s0);
    atomicAdd(acc + 8 + b, s1);
    atomicAdd(acc + 16 + b, s2);
    atomicAdd(acc + 24, s3);
  }
}

// One block per (b, y) output row. Phase 1: column distance at row y for all
// 256 columns (single pass over y' — only row y's value is needed). Phase 2:
// brute-force lower envelope over x' (matches reference exactly). Accumulate
// sum of probs * (d_pos + d_neg), gated by any_fg (sum_t > 0.5).
__global__ __launch_bounds__(256) void boundary_kernel(
    const float* __restrict__ probs, const int* __restrict__ targets,
    const float* __restrict__ acc, float* __restrict__ bsum) {
  const int blk = blockIdx.x;
  const int b = blk >> 8;
  const int y = blk & 255;
  const int x = threadIdx.x;
  const int* __restrict__ timg = targets + b * HW_ELEMS;

  float dpos = BIGD, dneg = BIGD;
  for (int yp = 0; yp < 256; ++yp) {
    const int tv = timg[yp * 256 + x];
    const float ady = fabsf((float)(y - yp));
    const float np = fminf(dpos, ady);
    const float nn = fminf(dneg, ady);
    dpos = tv ? np : dpos;
    dneg = tv ? dneg : nn;
  }

  __shared__ float g2p[256];
  __shared__ float g2n[256];
  g2p[x] = dpos * dpos;
  g2n[x] = dneg * dneg;
  __syncthreads();

  float m2p = 3.4e37f, m2n = 3.4e37f;
  #pragma unroll 4
  for (int xp = 0; xp < 256; ++xp) {
    const float dd = (float)(x - xp);
    const float d2 = dd * dd;
    m2p = fminf(m2p, d2 + g2p[xp]);
    m2n = fminf(m2n, d2 + g2n[xp]);
  }

  const float anyfg = (acc[16 + b] > 0.5f) ? 1.f : 0.f;
  const float sdt = sqrtf(m2p) + sqrtf(m2n);
  const float contrib = probs[b * HW_ELEMS + y * 256 + x] * sdt * anyfg;

  const float v = waveSum(contrib);
  __shared__ float lds[4];
  const int wid = threadIdx.x >> 6, lane = threadIdx.x & 63;
  if (lane == 0) lds[wid] = v;
  __syncthreads();
  if (threadIdx.x == 0) atomicAdd(bsum, lds[0] + lds[1] + lds[2] + lds[3]);
}

__global__ void finalize_kernel(const float* __restrict__ acc, float* __restrict__ out) {
  float dsum = 0.f, tsum = 0.f;
  #pragma unroll
  for (int b = 0; b < 8; ++b) {
    const float inter = acc[b], sp = acc[8 + b], st = acc[16 + b];
    dsum += (2.f * inter + EPSL) / (sp + st + EPSL);
    const float fn = st - inter;
    const float fp = sp - inter;
    tsum += (inter + EPSL) / (inter + 0.3f * fn + 0.7f * fp + EPSL);
  }
  const float dl = 1.f - dsum * 0.125f;
  const float tl = 1.f - tsum * 0.125f;
  const float bl = acc[25] * (1.f / 524288.f);
  const float al = acc[24] * (1.f / 524288.f);
  out[0] = 1.0f * dl + 0.7f * tl + 0.5f * bl + 0.3f * al;
}

extern "C" void kernel_launch(void* const* d_in, const int* in_sizes, int n_in,
                              void* d_out, int out_size, void* d_ws, size_t ws_size,
                              hipStream_t stream) {
  const float* probs   = (const float*)d_in[0];
  const int*   targets = (const int*)d_in[1];
  const float* attn    = (const float*)d_in[2];
  float* out = (float*)d_out;
  float* acc = (float*)d_ws;  // 26 floats used; poisoned 0xAA each call -> zero it
  hipMemsetAsync(acc, 0, 32 * sizeof(float), stream);
  dim3 rgrid(32, 8);
  reduce_kernel<<<rgrid, 256, 0, stream>>>(probs, targets, attn, acc);
  boundary_kernel<<<2048, 256, 0, stream>>>(probs, targets, acc, acc + 25);
  finalize_kernel<<<1, 1, 0, stream>>>(acc, out);
}